// Round 1
// baseline (328.242 us; speedup 1.0000x reference)
//
#include <hip/hip_runtime.h>
#include <hip/hip_bf16.h>

// Problem constants (from reference): B=512, T=64, A=32, H=512, E=32
#define B_ 512
#define T_ 64
#define A_ 32
#define H_ 512
#define E_ 32
#define MAX_TASKS 272   // sum_e ceil(cnt_e/2) <= 256 + 16
#define CAP_ 168        // itemlist capacity per XCD class
#define GRID_ (8 * CAP_)
#define SC 16           // tau-bias sample chunk

typedef unsigned short u16;
typedef unsigned int u32;
typedef __attribute__((ext_vector_type(8))) short short8;   // 8 bf16 (MFMA A/B frag)
typedef __attribute__((ext_vector_type(4))) float floatx4;  // MFMA C/D frag

static __device__ __forceinline__ u16 f2bf(float f) {
    u32 u = __builtin_bit_cast(u32, f);
    u += 0x7fffu + ((u >> 16) & 1u);   // RNE
    return (u16)(u >> 16);
}

// async global->LDS, 16B per lane; LDS dest is wave-uniform base (HW adds
// lane*16). Swizzle must be applied on the GLOBAL address per lane.
static __device__ __forceinline__ void gl2lds16(const u16* g, u16* l) {
    __builtin_amdgcn_global_load_lds(
        (const __attribute__((address_space(1))) void*)g,
        (__attribute__((address_space(3))) void*)l, 16, 0, 0);
}

// ---------------------------------------------------------------------------
// Kernel 1: group samples by expert, build 2-sample tasks, XCD-affinity
// itemlist (slot f -> XCD f%8; expert e -> XCD e%8). Also exports per-expert
// (off, cnt) for the tau-bias kernel. Skew overflow -> sequential fallback.
// ---------------------------------------------------------------------------
__global__ void group_kernel(const int* __restrict__ cat_ids,
                             int* __restrict__ sample_list,
                             int4* __restrict__ tasks,
                             int* __restrict__ itemlist,
                             int* __restrict__ eoff_g,
                             int* __restrict__ ecnt_g) {
    __shared__ int cnt[E_], off[E_], cur[E_], toff[E_], jc[8];
    __shared__ int total, fb;
    int tid = threadIdx.x;
    if (tid < E_) { cnt[tid] = 0; cur[tid] = 0; }
    __syncthreads();
    int e = cat_ids[tid];               // tid in [0,512) == B_
    atomicAdd(&cnt[e], 1);
    __syncthreads();
    if (tid == 0) {
        int run = 0, trun = 0;
        for (int i = 0; i < E_; i++) {
            off[i] = run;  run += cnt[i];
            toff[i] = trun; trun += (cnt[i] + 1) >> 1;
        }
        total = trun;
    }
    __syncthreads();
    if (tid < E_) {
        int c = cnt[tid], o = off[tid], to = toff[tid];
        eoff_g[tid] = o;
        ecnt_g[tid] = c;
        for (int j = 0; j < c; j += 2)
            tasks[to++] = make_int4(tid, o + j, (c - j >= 2) ? 2 : 1, 0);
    }
    if (tid < 8) {
        int J = 0;
        for (int cc = 0; cc < 4; cc++) J += 4 * ((cnt[tid + 8 * cc] + 1) >> 1);
        jc[tid] = J;
    }
    __syncthreads();
    if (tid == 0) {
        int f = 0;
        for (int x = 0; x < 8; x++) if (jc[x] > CAP_) f = 1;
        fb = f;
    }
    __syncthreads();
    if (!fb) {
        if (tid < 8) {
            int j = 0;
            for (int cc = 0; cc < 4; cc++) {
                int ee = tid + 8 * cc;
                int nt = (cnt[ee] + 1) >> 1, t0 = toff[ee];
                for (int t = t0; t < t0 + nt; t++)
                    for (int nb = 0; nb < 4; nb++) {
                        itemlist[tid + 8 * j] = (t << 2) | nb;
                        j++;
                    }
            }
            for (; j < CAP_; j++) itemlist[tid + 8 * j] = -1;
        }
    } else {
        for (int f = tid; f < GRID_; f += 512)
            itemlist[f] = (f < 4 * total) ? f : -1;
    }
    int p = atomicAdd(&cur[e], 1);
    sample_list[off[e] + p] = tid;
}

// ---------------------------------------------------------------------------
// Kernel 2: per-sample GEMM1 (K=32, fp32 VALU) -> bf16 a_emb. (tau handled
// entirely by tau_bias_kernel now — no bf16 tau round-trip.)
// ---------------------------------------------------------------------------
__global__ __launch_bounds__(256) void embed_kernel(
        const float* __restrict__ actions, const int* __restrict__ cat_ids,
        const float* __restrict__ W1, const float* __restrict__ b1,
        u16* __restrict__ a_emb) {
    int b = blockIdx.x;
    int tid = threadIdx.x;
    int e = cat_ids[b];

    __shared__ float act[T_ * A_];
    const float* asrc = actions + (size_t)b * T_ * A_;
    for (int i = tid; i < T_ * A_; i += 256) act[i] = asrc[i];
    __syncthreads();

    const float* w1 = W1 + (size_t)e * A_ * H_;
    int n0 = tid, n1 = tid + 256;
    float wA[A_], wB[A_];
#pragma unroll
    for (int k = 0; k < A_; k++) {
        wA[k] = w1[k * H_ + n0];
        wB[k] = w1[k * H_ + n1];
    }
    float bA = b1[e * H_ + n0], bB = b1[e * H_ + n1];
    u16* orow = a_emb + (size_t)b * T_ * H_;
    for (int tt = 0; tt < T_; tt++) {
        float accA = bA, accB = bB;
#pragma unroll
        for (int k = 0; k < A_; k++) {
            float a = act[tt * A_ + k];   // LDS broadcast
            accA = fmaf(a, wA[k], accA);
            accB = fmaf(a, wB[k], accB);
        }
        orow[tt * H_ + n0] = f2bf(accA);
        orow[tt * H_ + n1] = f2bf(accB);
    }
}

// ---------------------------------------------------------------------------
// Kernel 3: W [E][srcK][512] f32, rows [0,dstK) -> Wt [E][512][dstK] bf16.
// ---------------------------------------------------------------------------
__global__ __launch_bounds__(256) void convert_transpose(
        const float* __restrict__ W, u16* __restrict__ Wt, int srcK, int dstK) {
    int n = blockIdx.y * 256 + threadIdx.x;
    int k0 = blockIdx.x * 32;
    int e = blockIdx.z;
    const float* src = W + ((size_t)e * srcK + k0) * H_ + n;
    short8 out[4];
#pragma unroll
    for (int j = 0; j < 32; j++)
        out[j >> 3][j & 7] = (short)f2bf(src[(size_t)j * H_]);
    u16* dst = Wt + ((size_t)e * H_ + n) * dstK + k0;
#pragma unroll
    for (int c = 0; c < 4; c++) *(short8*)(dst + c * 8) = out[c];
}

// ---------------------------------------------------------------------------
// Kernel 4: per-sample GEMM2-bias: bias2s[s][n] = tau_f32(s) . W2b_f32[e] +
// b2[e][n]. tau is identical across the 64 timesteps of a sample, so this
// removes the whole K=[512,1024) half of GEMM2 (17.2 GFLOP of MFMA) for
// 0.27 GFLOP of fp32 VALU. Grid: (8 col-chunks of 64) x E. Per block:
// W2b[e][:, chunk] read once (128 KB); samples processed in chunks of SC=16
// with tau staged in LDS (broadcast reads); 4-way K-split across waves,
// LDS reduce. f32 end-to-end (more accurate than old bf16 tau path).
// ---------------------------------------------------------------------------
__global__ __launch_bounds__(256) void tau_bias_kernel(
        const float* __restrict__ W2, const float* __restrict__ b2,
        const float* __restrict__ timesteps, const int* __restrict__ sample_list,
        const int* __restrict__ eoff, const int* __restrict__ ecnt,
        float* __restrict__ bias2s) {
    int cc = blockIdx.x;          // 0..7: 64-col chunk
    int e = blockIdx.y;
    int cnt = ecnt[e], off = eoff[e];
    if (cnt == 0) return;
    int tid = threadIdx.x;
    int kq = tid >> 6, lane = tid & 63;
    int n = cc * 64 + lane;
    __shared__ float tauS[SC][512];     // 32 KB
    __shared__ float pS[4][SC][64];     // 16 KB
    const float* wb = W2 + ((size_t)e * 1024 + 512) * H_;   // W2b base [k][n]

    for (int c0 = 0; c0 < cnt; c0 += SC) {
        // stage tau rows for this sample chunk (f32, on-the-fly trig)
        for (int i = tid; i < SC * 512; i += 256) {
            int sl = i >> 9, k = i & 511;
            float v = 0.f;
            if (c0 + sl < cnt) {
                int s = sample_list[off + c0 + sl];
                float tval = timesteps[s];
                int kk = k & 255;
                float freq = expf(-9.210340371976184f * (float)kk * (1.0f / 256.0f));
                float ang = tval * freq;
                v = (k < 256) ? sinf(ang) : cosf(ang);
            }
            tauS[sl][k] = v;
        }
        __syncthreads();

        float a[SC];
#pragma unroll
        for (int s = 0; s < SC; s++) a[s] = 0.f;
        int kb = kq * 128;
        for (int k = kb; k < kb + 128; k += 4) {
            float w0 = wb[(size_t)k * H_ + n];          // 256B/wave coalesced
            float w1 = wb[(size_t)(k + 1) * H_ + n];
            float w2 = wb[(size_t)(k + 2) * H_ + n];
            float w3 = wb[(size_t)(k + 3) * H_ + n];
#pragma unroll
            for (int s = 0; s < SC; s++) {
                float4 t4 = *(const float4*)&tauS[s][k];  // LDS broadcast
                a[s] = fmaf(t4.x, w0, a[s]);
                a[s] = fmaf(t4.y, w1, a[s]);
                a[s] = fmaf(t4.z, w2, a[s]);
                a[s] = fmaf(t4.w, w3, a[s]);
            }
        }
#pragma unroll
        for (int s = 0; s < SC; s++) pS[kq][s][lane] = a[s];
        __syncthreads();

        for (int o = tid; o < SC * 64; o += 256) {
            int sl = o >> 6, ln = o & 63;
            if (c0 + sl < cnt) {
                float v = pS[0][sl][ln] + pS[1][sl][ln] +
                          pS[2][sl][ln] + pS[3][sl][ln];
                int s = sample_list[off + c0 + sl];
                int col = cc * 64 + ln;
                bias2s[(size_t)s * H_ + col] = v + b2[e * H_ + col];
            }
        }
        __syncthreads();
    }
}

// ---------------------------------------------------------------------------
// Kernels 5/6: expert-grouped MFMA GEMM, both now K=512 (tau folded out).
// Block: 256 threads (4 waves), tile M=128 (2 samples) x N=128, BK=64.
// NEW vs previous round: LDS double-buffered (2x32KB=64KB, 2 blocks/CU) with
// stage-before-compute: per K-iter, issue next tile's global_load_lds FIRST,
// then ds_read+MFMA current buffer, then ONE __syncthreads (its vmcnt(0)
// drain lands after ~400cy of compute covering the load latency). This
// replaces the old stage->sync->compute->sync structure whose staging
// latency was fully exposed every iteration (MfmaUtil 17%).
// Swizzle: 16B chunk c of row r at slot c^(r&7), applied on the global
// address side (gl2lds dest must be linear); frag reads 2-way aliased (free).
// ---------------------------------------------------------------------------
template <int DIN, bool PSBIAS, bool DO_SWISH, bool OUT_BF16>
__global__ __launch_bounds__(256, 2) void moe_gemm(
        const u16* __restrict__ xsrc, const u16* __restrict__ Wt,
        const float* __restrict__ bias,
        const int* __restrict__ sample_list, const int4* __restrict__ tasks,
        const int* __restrict__ itemlist, void* __restrict__ outp) {
    int item = itemlist[blockIdx.x];
    if (item < 0) return;
    int4 task = tasks[item >> 2];
    int nb = item & 3;
    int ns = task.z;
    int e = task.x;
    int s0 = sample_list[task.y];
    int s1 = (ns > 1) ? sample_list[task.y + 1] : s0;  // dup reads, masked store
    int n0 = nb * 128;

    int tid = threadIdx.x;
    int lane = tid & 63, wv = tid >> 6;          // 4 waves
    int wr = wv >> 1, wc = wv & 1;               // 2x2 wave grid
    int quad = lane >> 4, c15 = lane & 15;
    int r8 = lane >> 3, cg = lane & 7;           // staging: row-in-group, chunk

    __shared__ __align__(16) u16 xs[2][128 * 64];   // 2 x 16 KB
    __shared__ __align__(16) u16 wt[2][128 * 64];   // 2 x 16 KB

    floatx4 acc[4][4];
    floatx4 zero4 = {0.f, 0.f, 0.f, 0.f};
#pragma unroll
    for (int i = 0; i < 4; i++)
#pragma unroll
        for (int j = 0; j < 4; j++) acc[i][j] = zero4;

    const u16* wbase = Wt + (size_t)(e * H_ + n0) * DIN;
    int kc_sw = (cg ^ r8) * 8;                   // swizzled global k-offset

    auto stage = [&](int b, int k0) {
#pragma unroll
        for (int h = 0; h < 4; h++) {
            int rbase = h * 32 + wv * 8;         // wave-uniform row-group base
            int s = (h < 2) ? s0 : s1;
            int t = (rbase + r8) & 63;
            gl2lds16(xsrc + ((size_t)s * T_ + t) * H_ + k0 + kc_sw,
                     &xs[b][rbase * 64]);
        }
#pragma unroll
        for (int h = 0; h < 4; h++) {
            int nbase = h * 32 + wv * 8;
            gl2lds16(wbase + (size_t)(nbase + r8) * DIN + k0 + kc_sw,
                     &wt[b][nbase * 64]);
        }
    };

    auto compute = [&](int b) {
#pragma unroll
        for (int kk = 0; kk < 2; kk++) {
            int c = kk * 4 + quad;               // k-chunk index 0..7
            short8 af[4], bfr[4];
#pragma unroll
            for (int i = 0; i < 4; i++) {
                int row = wr * 64 + i * 16 + c15;
                af[i] = *(const short8*)&xs[b][row * 64 + ((c ^ (row & 7)) * 8)];
                int nr = wc * 64 + i * 16 + c15;
                bfr[i] = *(const short8*)&wt[b][nr * 64 + ((c ^ (nr & 7)) * 8)];
            }
#pragma unroll
            for (int mt = 0; mt < 4; mt++)
#pragma unroll
                for (int nt = 0; nt < 4; nt++)
                    acc[mt][nt] = __builtin_amdgcn_mfma_f32_16x16x32_bf16(
                            af[mt], bfr[nt], acc[mt][nt], 0, 0, 0);
        }
    };

    constexpr int KI = DIN / 64;                 // 8 K-iterations
    stage(0, 0);
    __syncthreads();                             // drain prologue stage
#pragma unroll
    for (int t = 0; t < KI; ++t) {
        if (t + 1 < KI) stage((t + 1) & 1, (t + 1) * 64);  // issue-early
        compute(t & 1);                          // overlaps in-flight stage
        if (t + 1 < KI) __syncthreads();         // vmcnt(0) drain + barrier
    }

    // ---- epilogue: C/D layout col=c15, row=quad*4+r; wave-row wr = sample ----
    if (wr >= ns) return;
    int s = (wr == 0) ? s0 : s1;
    const float* bp = PSBIAS ? (bias + (size_t)s * H_)   // per-sample (GEMM2)
                             : (bias + (size_t)e * H_);  // per-expert (GEMM3)
#pragma unroll
    for (int mt = 0; mt < 4; mt++) {
        int tb = mt * 16 + quad * 4;             // t base within sample
#pragma unroll
        for (int nt = 0; nt < 4; nt++) {
            int col = n0 + wc * 64 + nt * 16 + c15;
            float bv = bp[col];
#pragma unroll
            for (int r = 0; r < 4; r++) {
                float v = acc[mt][nt][r] + bv;
                if (DO_SWISH) v = v / (1.0f + expf(-v));   // x*sigmoid(x)
                size_t oidx = ((size_t)s * T_ + tb + r) * H_ + col;
                if (OUT_BF16) ((u16*)outp)[oidx] = f2bf(v);
                else          ((float*)outp)[oidx] = v;
            }
        }
    }
}

// ---------------------------------------------------------------------------
extern "C" void kernel_launch(void* const* d_in, const int* in_sizes, int n_in,
                              void* d_out, int out_size, void* d_ws, size_t ws_size,
                              hipStream_t stream) {
    const float* actions   = (const float*)d_in[0];
    const float* timesteps = (const float*)d_in[1];
    const int*   cat_ids   = (const int*)d_in[2];
    const float* W1 = (const float*)d_in[3];
    const float* b1 = (const float*)d_in[4];
    const float* W2 = (const float*)d_in[5];
    const float* b2 = (const float*)d_in[6];
    const float* W3 = (const float*)d_in[7];
    const float* b3 = (const float*)d_in[8];

    // ws: a_emb 32MB (reused as Wt3 after GEMM2) | y 32MB | (unused 512KB) |
    // meta. d_out (64MB) hosts Wt2a (16.8MB @0) + bias2s (1MB @48MB) —
    // scratch until GEMM3's epilogue overwrites d_out.
    char* ws = (char*)d_ws;
    u16* a_emb = (u16*)ws;
    u16* y     = (u16*)(ws + (size_t)32 * 1024 * 1024);
    char* meta = ws + (size_t)64 * 1024 * 1024 + 512 * 1024;
    int*  sample_list = (int*)meta;                     // 2 KB
    int4* tasks       = (int4*)(meta + 8192);           // 272*16 B
    int*  itemlist    = (int*)(meta + 16384);           // GRID_*4 B
    int*  eoff        = (int*)(meta + 24576);           // 128 B
    int*  ecnt        = (int*)(meta + 24576 + 128);     // 128 B
    u16*  Wt2a   = (u16*)d_out;
    float* bias2s = (float*)((char*)d_out + (size_t)48 * 1024 * 1024);
    u16*  Wt3    = a_emb;

    hipLaunchKernelGGL(group_kernel, dim3(1), dim3(512), 0, stream,
                       cat_ids, sample_list, tasks, itemlist, eoff, ecnt);
    hipLaunchKernelGGL(embed_kernel, dim3(512), dim3(256), 0, stream,
                       actions, cat_ids, W1, b1, a_emb);
    hipLaunchKernelGGL(convert_transpose, dim3(H_ / 32, 2, E_), dim3(256),
                       0, stream, W2, Wt2a, 2 * H_, H_);
    hipLaunchKernelGGL(tau_bias_kernel, dim3(8, E_), dim3(256), 0, stream,
                       W2, b2, timesteps, sample_list, eoff, ecnt, bias2s);
    hipLaunchKernelGGL((moe_gemm<H_, true, true, true>), dim3(GRID_),
                       dim3(256), 0, stream,
                       a_emb, Wt2a, bias2s, sample_list, tasks, itemlist,
                       (void*)y);
    hipLaunchKernelGGL(convert_transpose, dim3(H_ / 32, 2, E_), dim3(256),
                       0, stream, W3, Wt3, H_, H_);
    hipLaunchKernelGGL((moe_gemm<H_, false, false, false>), dim3(GRID_),
                       dim3(256), 0, stream,
                       y, Wt3, b3, sample_list, tasks, itemlist, d_out);
}

// Round 2
// 318.643 us; speedup vs baseline: 1.0301x; 1.0301x over previous
//
#include <hip/hip_runtime.h>
#include <hip/hip_bf16.h>

// Problem constants (from reference): B=512, T=64, A=32, H=512, E=32
#define B_ 512
#define T_ 64
#define A_ 32
#define H_ 512
#define E_ 32
#define MAX_TASKS 272   // sum_e ceil(cnt_e/2) <= 256 + 16
#define CAP_ 168        // itemlist capacity per XCD class
#define GRID_ (8 * CAP_)
#define TSC 16          // tau-bias samples per chunk

typedef unsigned short u16;
typedef unsigned int u32;
typedef __attribute__((ext_vector_type(8))) short short8;   // 8 bf16 (MFMA A/B frag)
typedef __attribute__((ext_vector_type(4))) float floatx4;  // MFMA C/D frag

static __device__ __forceinline__ u16 f2bf(float f) {
    u32 u = __builtin_bit_cast(u32, f);
    u += 0x7fffu + ((u >> 16) & 1u);   // RNE
    return (u16)(u >> 16);
}

// async global->LDS, 16B per lane; LDS dest is wave-uniform base (HW adds
// lane*16). Swizzle must be applied on the GLOBAL address per lane.
static __device__ __forceinline__ void gl2lds16(const u16* g, u16* l) {
    __builtin_amdgcn_global_load_lds(
        (const __attribute__((address_space(1))) void*)g,
        (__attribute__((address_space(3))) void*)l, 16, 0, 0);
}

// ---------------------------------------------------------------------------
// Kernel 1: group samples by expert, build 2-sample tasks, XCD-affinity
// itemlist (slot f -> XCD f%8; expert e -> XCD e%8). Also exports per-expert
// (off, cnt) for the tau-bias kernel. Skew overflow -> sequential fallback.
// ---------------------------------------------------------------------------
__global__ void group_kernel(const int* __restrict__ cat_ids,
                             int* __restrict__ sample_list,
                             int4* __restrict__ tasks,
                             int* __restrict__ itemlist,
                             int* __restrict__ eoff_g,
                             int* __restrict__ ecnt_g) {
    __shared__ int cnt[E_], off[E_], cur[E_], toff[E_], jc[8];
    __shared__ int total, fb;
    int tid = threadIdx.x;
    if (tid < E_) { cnt[tid] = 0; cur[tid] = 0; }
    __syncthreads();
    int e = cat_ids[tid];               // tid in [0,512) == B_
    atomicAdd(&cnt[e], 1);
    __syncthreads();
    if (tid == 0) {
        int run = 0, trun = 0;
        for (int i = 0; i < E_; i++) {
            off[i] = run;  run += cnt[i];
            toff[i] = trun; trun += (cnt[i] + 1) >> 1;
        }
        total = trun;
    }
    __syncthreads();
    if (tid < E_) {
        int c = cnt[tid], o = off[tid], to = toff[tid];
        eoff_g[tid] = o;
        ecnt_g[tid] = c;
        for (int j = 0; j < c; j += 2)
            tasks[to++] = make_int4(tid, o + j, (c - j >= 2) ? 2 : 1, 0);
    }
    if (tid < 8) {
        int J = 0;
        for (int cc = 0; cc < 4; cc++) J += 4 * ((cnt[tid + 8 * cc] + 1) >> 1);
        jc[tid] = J;
    }
    __syncthreads();
    if (tid == 0) {
        int f = 0;
        for (int x = 0; x < 8; x++) if (jc[x] > CAP_) f = 1;
        fb = f;
    }
    __syncthreads();
    if (!fb) {
        if (tid < 8) {
            int j = 0;
            for (int cc = 0; cc < 4; cc++) {
                int ee = tid + 8 * cc;
                int nt = (cnt[ee] + 1) >> 1, t0 = toff[ee];
                for (int t = t0; t < t0 + nt; t++)
                    for (int nb = 0; nb < 4; nb++) {
                        itemlist[tid + 8 * j] = (t << 2) | nb;
                        j++;
                    }
            }
            for (; j < CAP_; j++) itemlist[tid + 8 * j] = -1;
        }
    } else {
        for (int f = tid; f < GRID_; f += 512)
            itemlist[f] = (f < 4 * total) ? f : -1;
    }
    int p = atomicAdd(&cur[e], 1);
    sample_list[off[e] + p] = tid;
}

// ---------------------------------------------------------------------------
// Kernel 2: per-sample GEMM1 (K=32, fp32 VALU) -> bf16 a_emb. Also emits the
// f32 tau table tauG[s][512] (2 trig evals/thread) consumed by tau_bias.
// ---------------------------------------------------------------------------
__global__ __launch_bounds__(256) void embed_kernel(
        const float* __restrict__ actions, const float* __restrict__ timesteps,
        const int* __restrict__ cat_ids, const float* __restrict__ W1,
        const float* __restrict__ b1, u16* __restrict__ a_emb,
        float* __restrict__ tauG) {
    int b = blockIdx.x;
    int tid = threadIdx.x;
    int e = cat_ids[b];

    {
        float tval = timesteps[b];
        float freq = expf(-9.210340371976184f * (float)tid * (1.0f / 256.0f));
        float ang = tval * freq;
        tauG[(size_t)b * H_ + tid]       = sinf(ang);
        tauG[(size_t)b * H_ + 256 + tid] = cosf(ang);
    }

    __shared__ float act[T_ * A_];
    const float* asrc = actions + (size_t)b * T_ * A_;
    for (int i = tid; i < T_ * A_; i += 256) act[i] = asrc[i];
    __syncthreads();

    const float* w1 = W1 + (size_t)e * A_ * H_;
    int n0 = tid, n1 = tid + 256;
    float wA[A_], wB[A_];
#pragma unroll
    for (int k = 0; k < A_; k++) {
        wA[k] = w1[k * H_ + n0];
        wB[k] = w1[k * H_ + n1];
    }
    float bA = b1[e * H_ + n0], bB = b1[e * H_ + n1];
    u16* orow = a_emb + (size_t)b * T_ * H_;
    for (int tt = 0; tt < T_; tt++) {
        float accA = bA, accB = bB;
#pragma unroll
        for (int k = 0; k < A_; k++) {
            float a = act[tt * A_ + k];   // LDS broadcast
            accA = fmaf(a, wA[k], accA);
            accB = fmaf(a, wB[k], accB);
        }
        orow[tt * H_ + n0] = f2bf(accA);
        orow[tt * H_ + n1] = f2bf(accB);
    }
}

// ---------------------------------------------------------------------------
// Kernel 3: W [E][srcK][512] f32, rows [0,dstK) -> Wt [E][512][dstK] bf16.
// ---------------------------------------------------------------------------
__global__ __launch_bounds__(256) void convert_transpose(
        const float* __restrict__ W, u16* __restrict__ Wt, int srcK, int dstK) {
    int n = blockIdx.y * 256 + threadIdx.x;
    int k0 = blockIdx.x * 32;
    int e = blockIdx.z;
    const float* src = W + ((size_t)e * srcK + k0) * H_ + n;
    short8 out[4];
#pragma unroll
    for (int j = 0; j < 32; j++)
        out[j >> 3][j & 7] = (short)f2bf(src[(size_t)j * H_]);
    u16* dst = Wt + ((size_t)e * H_ + n) * dstK + k0;
#pragma unroll
    for (int c = 0; c < 4; c++) *(short8*)(dst + c * 8) = out[c];
}

// ---------------------------------------------------------------------------
// Kernel 4 (REWRITTEN): bias2s[s][n] = tauG_f32[s] . W2b_f32[e] + b2[e][n].
// Old version: 256 blocks, on-device trig redone 8x/expert, 4-deep load ILP,
// 3 syncs/chunk -> 58 us pure-latency (VALU 14%, HBM 5%, occ 7%).
// New: tau table precomputed (embed); per block (8cc x E): stage 16 tau rows
// TRANSPOSED into LDS [k][16] once; fixed-trip 64-iter k-loop, unroll 8
// (~16 global loads in flight); each thread 2 cols -> per k: 4 ds_read_b128
// broadcasts feed 32 FMAs (FMA-issue >= LDS-issue). k8-split reduced via
// __shfl_xor(32) then 16KB LDS. W2b read exactly once (33.5 MB total).
// LDS floor: 64 iter x 4 waves x 48cy = 12k cy/CU ~ 5 us.
// ---------------------------------------------------------------------------
__global__ __launch_bounds__(256) void tau_bias_kernel(
        const float* __restrict__ W2, const float* __restrict__ b2,
        const float* __restrict__ tauG, const int* __restrict__ sample_list,
        const int* __restrict__ eoff, const int* __restrict__ ecnt,
        float* __restrict__ bias2s) {
    int cc = blockIdx.x;          // 0..7: 64-col chunk
    int e = blockIdx.y;
    int cnt = ecnt[e], off = eoff[e];
    if (cnt == 0) return;
    int tid = threadIdx.x;
    int k8 = tid >> 5, ln = tid & 31;  // k-residue 0..7, col-in-chunk 0..31
    int wv = tid >> 6;
    int n0 = cc * 64 + ln, n1 = n0 + 32;
    const float* wb = W2 + ((size_t)e * 1024 + 512) * H_;   // W2b base [k][n]

    __shared__ float tauT[512][20];    // [k][sl], pad 20: rows 80B (16B-align,
                                       // writes spread over 8 banks) — 40 KB
    __shared__ float pS[4][TSC][64];   // per-wave partials — 16 KB

    for (int c0 = 0; c0 < cnt; c0 += TSC) {
        // stage tau rows transposed: global reads coalesced along k
        for (int i = tid; i < TSC * 512; i += 256) {
            int sl = i >> 9, k = i & 511;
            float v = 0.f;
            if (c0 + sl < cnt)
                v = tauG[(size_t)sample_list[off + c0 + sl] * H_ + k];
            tauT[k][sl] = v;
        }
        __syncthreads();

        float a0[TSC], a1[TSC];
#pragma unroll
        for (int s = 0; s < TSC; s++) { a0[s] = 0.f; a1[s] = 0.f; }

#pragma unroll 8
        for (int j = 0; j < 64; j++) {
            int k = k8 + j * 8;
            float w0 = wb[(size_t)k * H_ + n0];   // 2x128B segments/wave
            float w1 = wb[(size_t)k * H_ + n1];
            float tv[TSC];
            *(float4*)&tv[0]  = *(const float4*)&tauT[k][0];   // broadcast
            *(float4*)&tv[4]  = *(const float4*)&tauT[k][4];
            *(float4*)&tv[8]  = *(const float4*)&tauT[k][8];
            *(float4*)&tv[12] = *(const float4*)&tauT[k][12];
#pragma unroll
            for (int s = 0; s < TSC; s++) {
                a0[s] = fmaf(tv[s], w0, a0[s]);
                a1[s] = fmaf(tv[s], w1, a1[s]);
            }
        }

        // fold the two k8-halves of each wave (lanes l and l+32 share n,s)
#pragma unroll
        for (int s = 0; s < TSC; s++) {
            a0[s] += __shfl_xor(a0[s], 32, 64);
            a1[s] += __shfl_xor(a1[s], 32, 64);
        }
        if (!(tid & 32)) {
#pragma unroll
            for (int s = 0; s < TSC; s++) {
                pS[wv][s][ln]      = a0[s];
                pS[wv][s][ln + 32] = a1[s];
            }
        }
        __syncthreads();

        for (int o = tid; o < TSC * 64; o += 256) {
            int sl = o >> 6, l = o & 63;
            if (c0 + sl < cnt) {
                float v = pS[0][sl][l] + pS[1][sl][l] +
                          pS[2][sl][l] + pS[3][sl][l];
                int s = sample_list[off + c0 + sl];
                int col = cc * 64 + l;
                bias2s[(size_t)s * H_ + col] = v + b2[e * H_ + col];
            }
        }
        __syncthreads();
    }
}

// ---------------------------------------------------------------------------
// Kernels 5/6: expert-grouped MFMA GEMM, both K=512 (tau folded out).
// Block: 256 threads (4 waves), tile M=128 (2 samples) x N=128, BK=64.
// LDS double-buffered (2x32KB) with stage-before-compute: per K-iter, issue
// next tile's global_load_lds FIRST, then ds_read+MFMA current buffer, then
// ONE __syncthreads (vmcnt(0) drain lands after ~400cy of covering compute).
// Swizzle: 16B chunk c of row r at slot c^(r&7), applied on the global
// address side (gl2lds dest must be linear); frag reads 2-way aliased (free).
// ---------------------------------------------------------------------------
template <int DIN, bool PSBIAS, bool DO_SWISH, bool OUT_BF16>
__global__ __launch_bounds__(256, 2) void moe_gemm(
        const u16* __restrict__ xsrc, const u16* __restrict__ Wt,
        const float* __restrict__ bias,
        const int* __restrict__ sample_list, const int4* __restrict__ tasks,
        const int* __restrict__ itemlist, void* __restrict__ outp) {
    int item = itemlist[blockIdx.x];
    if (item < 0) return;
    int4 task = tasks[item >> 2];
    int nb = item & 3;
    int ns = task.z;
    int e = task.x;
    int s0 = sample_list[task.y];
    int s1 = (ns > 1) ? sample_list[task.y + 1] : s0;  // dup reads, masked store
    int n0 = nb * 128;

    int tid = threadIdx.x;
    int lane = tid & 63, wv = tid >> 6;          // 4 waves
    int wr = wv >> 1, wc = wv & 1;               // 2x2 wave grid
    int quad = lane >> 4, c15 = lane & 15;
    int r8 = lane >> 3, cg = lane & 7;           // staging: row-in-group, chunk

    __shared__ __align__(16) u16 xs[2][128 * 64];   // 2 x 16 KB
    __shared__ __align__(16) u16 wt[2][128 * 64];   // 2 x 16 KB

    floatx4 acc[4][4];
    floatx4 zero4 = {0.f, 0.f, 0.f, 0.f};
#pragma unroll
    for (int i = 0; i < 4; i++)
#pragma unroll
        for (int j = 0; j < 4; j++) acc[i][j] = zero4;

    const u16* wbase = Wt + (size_t)(e * H_ + n0) * DIN;
    int kc_sw = (cg ^ r8) * 8;                   // swizzled global k-offset

    auto stage = [&](int b, int k0) {
#pragma unroll
        for (int h = 0; h < 4; h++) {
            int rbase = h * 32 + wv * 8;         // wave-uniform row-group base
            int s = (h < 2) ? s0 : s1;
            int t = (rbase + r8) & 63;
            gl2lds16(xsrc + ((size_t)s * T_ + t) * H_ + k0 + kc_sw,
                     &xs[b][rbase * 64]);
        }
#pragma unroll
        for (int h = 0; h < 4; h++) {
            int nbase = h * 32 + wv * 8;
            gl2lds16(wbase + (size_t)(nbase + r8) * DIN + k0 + kc_sw,
                     &wt[b][nbase * 64]);
        }
    };

    auto compute = [&](int b) {
#pragma unroll
        for (int kk = 0; kk < 2; kk++) {
            int c = kk * 4 + quad;               // k-chunk index 0..7
            short8 af[4], bfr[4];
#pragma unroll
            for (int i = 0; i < 4; i++) {
                int row = wr * 64 + i * 16 + c15;
                af[i] = *(const short8*)&xs[b][row * 64 + ((c ^ (row & 7)) * 8)];
                int nr = wc * 64 + i * 16 + c15;
                bfr[i] = *(const short8*)&wt[b][nr * 64 + ((c ^ (nr & 7)) * 8)];
            }
#pragma unroll
            for (int mt = 0; mt < 4; mt++)
#pragma unroll
                for (int nt = 0; nt < 4; nt++)
                    acc[mt][nt] = __builtin_amdgcn_mfma_f32_16x16x32_bf16(
                            af[mt], bfr[nt], acc[mt][nt], 0, 0, 0);
        }
    };

    constexpr int KI = DIN / 64;                 // 8 K-iterations
    stage(0, 0);
    __syncthreads();                             // drain prologue stage
#pragma unroll
    for (int t = 0; t < KI; ++t) {
        if (t + 1 < KI) stage((t + 1) & 1, (t + 1) * 64);  // issue-early
        compute(t & 1);                          // overlaps in-flight stage
        if (t + 1 < KI) __syncthreads();         // vmcnt(0) drain + barrier
    }

    // ---- epilogue: C/D layout col=c15, row=quad*4+r; wave-row wr = sample ----
    if (wr >= ns) return;
    int s = (wr == 0) ? s0 : s1;
    const float* bp = PSBIAS ? (bias + (size_t)s * H_)   // per-sample (GEMM2)
                             : (bias + (size_t)e * H_);  // per-expert (GEMM3)
#pragma unroll
    for (int mt = 0; mt < 4; mt++) {
        int tb = mt * 16 + quad * 4;             // t base within sample
#pragma unroll
        for (int nt = 0; nt < 4; nt++) {
            int col = n0 + wc * 64 + nt * 16 + c15;
            float bv = bp[col];
#pragma unroll
            for (int r = 0; r < 4; r++) {
                float v = acc[mt][nt][r] + bv;
                if (DO_SWISH) v = v / (1.0f + expf(-v));   // x*sigmoid(x)
                size_t oidx = ((size_t)s * T_ + tb + r) * H_ + col;
                if (OUT_BF16) ((u16*)outp)[oidx] = f2bf(v);
                else          ((float*)outp)[oidx] = v;
            }
        }
    }
}

// ---------------------------------------------------------------------------
extern "C" void kernel_launch(void* const* d_in, const int* in_sizes, int n_in,
                              void* d_out, int out_size, void* d_ws, size_t ws_size,
                              hipStream_t stream) {
    const float* actions   = (const float*)d_in[0];
    const float* timesteps = (const float*)d_in[1];
    const int*   cat_ids   = (const int*)d_in[2];
    const float* W1 = (const float*)d_in[3];
    const float* b1 = (const float*)d_in[4];
    const float* W2 = (const float*)d_in[5];
    const float* b2 = (const float*)d_in[6];
    const float* W3 = (const float*)d_in[7];
    const float* b3 = (const float*)d_in[8];

    // ws: a_emb 32MB (reused as Wt3 after GEMM2) | y 32MB | meta.
    // d_out (64 MiB) is scratch until GEMM3's epilogue:
    //   Wt2a bf16 16MiB @0 | bias2s f32 1MiB @48MiB | tauG f32 1MiB @52MiB.
    char* ws = (char*)d_ws;
    u16* a_emb = (u16*)ws;
    u16* y     = (u16*)(ws + (size_t)32 * 1024 * 1024);
    char* meta = ws + (size_t)64 * 1024 * 1024 + 512 * 1024;
    int*  sample_list = (int*)meta;                     // 2 KB
    int4* tasks       = (int4*)(meta + 8192);           // 272*16 B
    int*  itemlist    = (int*)(meta + 16384);           // GRID_*4 B
    int*  eoff        = (int*)(meta + 24576);           // 128 B
    int*  ecnt        = (int*)(meta + 24576 + 128);     // 128 B
    u16*  Wt2a   = (u16*)d_out;
    float* bias2s = (float*)((char*)d_out + (size_t)48 * 1024 * 1024);
    float* tauG   = (float*)((char*)d_out + (size_t)52 * 1024 * 1024);
    u16*  Wt3    = a_emb;

    hipLaunchKernelGGL(group_kernel, dim3(1), dim3(512), 0, stream,
                       cat_ids, sample_list, tasks, itemlist, eoff, ecnt);
    hipLaunchKernelGGL(embed_kernel, dim3(512), dim3(256), 0, stream,
                       actions, timesteps, cat_ids, W1, b1, a_emb, tauG);
    hipLaunchKernelGGL(convert_transpose, dim3(H_ / 32, 2, E_), dim3(256),
                       0, stream, W2, Wt2a, 2 * H_, H_);
    hipLaunchKernelGGL(tau_bias_kernel, dim3(8, E_), dim3(256), 0, stream,
                       W2, b2, tauG, sample_list, eoff, ecnt, bias2s);
    hipLaunchKernelGGL((moe_gemm<H_, true, true, true>), dim3(GRID_),
                       dim3(256), 0, stream,
                       a_emb, Wt2a, bias2s, sample_list, tasks, itemlist,
                       (void*)y);
    hipLaunchKernelGGL(convert_transpose, dim3(H_ / 32, 2, E_), dim3(256),
                       0, stream, W3, Wt3, H_, H_);
    hipLaunchKernelGGL((moe_gemm<H_, false, false, false>), dim3(GRID_),
                       dim3(256), 0, stream,
                       y, Wt3, b3, sample_list, tasks, itemlist, d_out);
}

// Round 3
// 303.346 us; speedup vs baseline: 1.0821x; 1.0504x over previous
//
#include <hip/hip_runtime.h>
#include <hip/hip_bf16.h>

// Problem constants (from reference): B=512, T=64, A=32, H=512, E=32
#define B_ 512
#define T_ 64
#define A_ 32
#define H_ 512
#define E_ 32
#define MAX_TASKS 272   // sum_e ceil(cnt_e/2) <= 256 + 16
#define CAP_ 168        // itemlist capacity per XCD class
#define GRID_ (8 * CAP_)
#define TSC 16          // tau-bias samples per chunk

typedef unsigned short u16;
typedef unsigned int u32;
typedef __attribute__((ext_vector_type(8))) short short8;   // 8 bf16 (MFMA A/B frag)
typedef __attribute__((ext_vector_type(4))) float floatx4;  // MFMA C/D frag

static __device__ __forceinline__ u16 f2bf(float f) {
    u32 u = __builtin_bit_cast(u32, f);
    u += 0x7fffu + ((u >> 16) & 1u);   // RNE
    return (u16)(u >> 16);
}

// async global->LDS, 16B per lane; LDS dest is wave-uniform base (HW adds
// lane*16). Swizzle must be applied on the GLOBAL address per lane.
static __device__ __forceinline__ void gl2lds16(const u16* g, u16* l) {
    __builtin_amdgcn_global_load_lds(
        (const __attribute__((address_space(1))) void*)g,
        (__attribute__((address_space(3))) void*)l, 16, 0, 0);
}

// ---------------------------------------------------------------------------
// Kernel 1: group samples by expert, build 2-sample tasks, XCD-affinity
// itemlist (slot f -> XCD f%8; expert e -> XCD e%8). Also exports per-expert
// (off, cnt) for the tau-bias kernel. Skew overflow -> sequential fallback.
// ---------------------------------------------------------------------------
__global__ void group_kernel(const int* __restrict__ cat_ids,
                             int* __restrict__ sample_list,
                             int4* __restrict__ tasks,
                             int* __restrict__ itemlist,
                             int* __restrict__ eoff_g,
                             int* __restrict__ ecnt_g) {
    __shared__ int cnt[E_], off[E_], cur[E_], toff[E_], jc[8];
    __shared__ int total, fb;
    int tid = threadIdx.x;
    if (tid < E_) { cnt[tid] = 0; cur[tid] = 0; }
    __syncthreads();
    int e = cat_ids[tid];               // tid in [0,512) == B_
    atomicAdd(&cnt[e], 1);
    __syncthreads();
    if (tid == 0) {
        int run = 0, trun = 0;
        for (int i = 0; i < E_; i++) {
            off[i] = run;  run += cnt[i];
            toff[i] = trun; trun += (cnt[i] + 1) >> 1;
        }
        total = trun;
    }
    __syncthreads();
    if (tid < E_) {
        int c = cnt[tid], o = off[tid], to = toff[tid];
        eoff_g[tid] = o;
        ecnt_g[tid] = c;
        for (int j = 0; j < c; j += 2)
            tasks[to++] = make_int4(tid, o + j, (c - j >= 2) ? 2 : 1, 0);
    }
    if (tid < 8) {
        int J = 0;
        for (int cc = 0; cc < 4; cc++) J += 4 * ((cnt[tid + 8 * cc] + 1) >> 1);
        jc[tid] = J;
    }
    __syncthreads();
    if (tid == 0) {
        int f = 0;
        for (int x = 0; x < 8; x++) if (jc[x] > CAP_) f = 1;
        fb = f;
    }
    __syncthreads();
    if (!fb) {
        if (tid < 8) {
            int j = 0;
            for (int cc = 0; cc < 4; cc++) {
                int ee = tid + 8 * cc;
                int nt = (cnt[ee] + 1) >> 1, t0 = toff[ee];
                for (int t = t0; t < t0 + nt; t++)
                    for (int nb = 0; nb < 4; nb++) {
                        itemlist[tid + 8 * j] = (t << 2) | nb;
                        j++;
                    }
            }
            for (; j < CAP_; j++) itemlist[tid + 8 * j] = -1;
        }
    } else {
        for (int f = tid; f < GRID_; f += 512)
            itemlist[f] = (f < 4 * total) ? f : -1;
    }
    int p = atomicAdd(&cur[e], 1);
    sample_list[off[e] + p] = tid;
}

// ---------------------------------------------------------------------------
// Kernel 2: per-sample GEMM1 (K=32, fp32 VALU) -> bf16 a_emb. Also emits the
// f32 tau table tauG[s][512] (2 trig evals/thread) and initializes
// bias2s[s][:] = b2[e(s)][:] (accumulated into by tau_bias_kernel next).
// ---------------------------------------------------------------------------
__global__ __launch_bounds__(256) void embed_kernel(
        const float* __restrict__ actions, const float* __restrict__ timesteps,
        const int* __restrict__ cat_ids, const float* __restrict__ W1,
        const float* __restrict__ b1, const float* __restrict__ b2,
        u16* __restrict__ a_emb, float* __restrict__ tauG,
        float* __restrict__ bias2s) {
    int b = blockIdx.x;
    int tid = threadIdx.x;
    int e = cat_ids[b];

    {
        float tval = timesteps[b];
        float freq = expf(-9.210340371976184f * (float)tid * (1.0f / 256.0f));
        float ang = tval * freq;
        tauG[(size_t)b * H_ + tid]       = sinf(ang);
        tauG[(size_t)b * H_ + 256 + tid] = cosf(ang);
        bias2s[(size_t)b * H_ + tid]       = b2[e * H_ + tid];
        bias2s[(size_t)b * H_ + 256 + tid] = b2[e * H_ + 256 + tid];
    }

    __shared__ float act[T_ * A_];
    const float* asrc = actions + (size_t)b * T_ * A_;
    for (int i = tid; i < T_ * A_; i += 256) act[i] = asrc[i];
    __syncthreads();

    const float* w1 = W1 + (size_t)e * A_ * H_;
    int n0 = tid, n1 = tid + 256;
    float wA[A_], wB[A_];
#pragma unroll
    for (int k = 0; k < A_; k++) {
        wA[k] = w1[k * H_ + n0];
        wB[k] = w1[k * H_ + n1];
    }
    float bA = b1[e * H_ + n0], bB = b1[e * H_ + n1];
    u16* orow = a_emb + (size_t)b * T_ * H_;
    for (int tt = 0; tt < T_; tt++) {
        float accA = bA, accB = bB;
#pragma unroll
        for (int k = 0; k < A_; k++) {
            float a = act[tt * A_ + k];   // LDS broadcast
            accA = fmaf(a, wA[k], accA);
            accB = fmaf(a, wB[k], accB);
        }
        orow[tt * H_ + n0] = f2bf(accA);
        orow[tt * H_ + n1] = f2bf(accB);
    }
}

// ---------------------------------------------------------------------------
// Kernel 3: W [E][srcK][512] f32, rows [0,dstK) -> Wt [E][512][dstK] bf16.
// Blocks cover 64 k so each thread writes a full 128B contiguous run of its
// Wt row (whole L2 lines covered by one thread -> no HBM write amplification).
// ---------------------------------------------------------------------------
__global__ __launch_bounds__(256) void convert_transpose(
        const float* __restrict__ W, u16* __restrict__ Wt, int srcK, int dstK) {
    int n = blockIdx.y * 256 + threadIdx.x;
    int k0 = blockIdx.x * 64;
    int e = blockIdx.z;
    const float* src = W + ((size_t)e * srcK + k0) * H_ + n;
    short8 out[8];
#pragma unroll
    for (int j = 0; j < 64; j++)
        out[j >> 3][j & 7] = (short)f2bf(src[(size_t)j * H_]);
    u16* dst = Wt + ((size_t)e * H_ + n) * dstK + k0;
#pragma unroll
    for (int c = 0; c < 8; c++) *(short8*)(dst + c * 8) = out[c];
}

// ---------------------------------------------------------------------------
// Kernel 4 (REWRITTEN again): bias2s[s][n] += tauG_f32[s] . W2b_f32[e].
// Round-2 post-mortem: 48 us, VALU 7.7%, occ 7% -> grid was 256 blocks =
// 1 block/CU = 1 wave/SIMD: pure TLP starvation; ILP can't save it.
// Fix: split K into 4 quarters -> grid (8cc x 32e x 4kq) = 1024 blocks =
// 4 blocks/CU = 16 waves/CU. Per block: 128k x 64cols x cnt samples
// (chunks of 16). W2b still read exactly once chip-wide (33.5 MB).
// k-quarter partials combined with hw f32 atomics into bias2s (pre-init'd
// to b2 by embed_kernel). LDS 26KB: tauT [128][20] (16B-aligned rows for
// float4 broadcast reads) + pS reduce buffer.
// ---------------------------------------------------------------------------
__global__ __launch_bounds__(256) void tau_bias_kernel(
        const float* __restrict__ W2, const float* __restrict__ tauG,
        const int* __restrict__ sample_list,
        const int* __restrict__ eoff, const int* __restrict__ ecnt,
        float* __restrict__ bias2s) {
    int cc = blockIdx.x;          // 0..7: 64-col chunk
    int e  = blockIdx.y;
    int kq = blockIdx.z;          // 0..3: 128-k quarter
    int cnt = ecnt[e], off = eoff[e];
    if (cnt == 0) return;
    int tid = threadIdx.x;
    int ks = tid >> 6;            // wave id = 32-k sub-block
    int ln = tid & 63;            // col within chunk
    int n = cc * 64 + ln;
    const float* wb = W2 + ((size_t)e * 1024 + 512 + kq * 128) * H_; // [k][n]

    __shared__ float tauT[128][20];    // [k][sl], rows 80B (16B-aligned) 10KB
    __shared__ float pS[4][TSC][64];   // per-wave partials — 16 KB

    for (int c0 = 0; c0 < cnt; c0 += TSC) {
        // stage tau slice transposed: [k][sl]; global reads 512B/row segments
        for (int i = tid; i < TSC * 128; i += 256) {
            int sl = i >> 7, k = i & 127;
            float v = 0.f;
            if (c0 + sl < cnt)
                v = tauG[(size_t)sample_list[off + c0 + sl] * H_ + kq * 128 + k];
            tauT[k][sl] = v;
        }
        __syncthreads();

        float a[TSC];
#pragma unroll
        for (int s = 0; s < TSC; s++) a[s] = 0.f;

#pragma unroll 8
        for (int j = 0; j < 32; j++) {
            int k = ks * 32 + j;
            float w = wb[(size_t)k * H_ + n];     // 256B/wave coalesced
            float tv[TSC];
            *(float4*)&tv[0]  = *(const float4*)&tauT[k][0];   // broadcast
            *(float4*)&tv[4]  = *(const float4*)&tauT[k][4];
            *(float4*)&tv[8]  = *(const float4*)&tauT[k][8];
            *(float4*)&tv[12] = *(const float4*)&tauT[k][12];
#pragma unroll
            for (int s = 0; s < TSC; s++) a[s] = fmaf(tv[s], w, a[s]);
        }

#pragma unroll
        for (int s = 0; s < TSC; s++) pS[ks][s][ln] = a[s];
        __syncthreads();

        for (int o = tid; o < TSC * 64; o += 256) {
            int sl = o >> 6, l = o & 63;
            if (c0 + sl < cnt) {
                float v = pS[0][sl][l] + pS[1][sl][l] +
                          pS[2][sl][l] + pS[3][sl][l];
                int s = sample_list[off + c0 + sl];
                unsafeAtomicAdd(&bias2s[(size_t)s * H_ + cc * 64 + l], v);
            }
        }
        __syncthreads();
    }
}

// ---------------------------------------------------------------------------
// Kernels 5/6: expert-grouped MFMA GEMM, both K=512 (tau folded out).
// Block: 256 threads (4 waves), tile M=128 (2 samples) x N=128, BK=64.
// LDS double-buffered (2x32KB) with stage-before-compute: per K-iter, issue
// next tile's global_load_lds FIRST, then ds_read+MFMA current buffer, then
// ONE __syncthreads (vmcnt(0) drain lands after ~400cy of covering compute).
// Swizzle: 16B chunk c of row r at slot c^(r&7), applied on the global
// address side (gl2lds dest must be linear); frag reads 2-way aliased (free).
// ---------------------------------------------------------------------------
template <int DIN, bool PSBIAS, bool DO_SWISH, bool OUT_BF16>
__global__ __launch_bounds__(256, 2) void moe_gemm(
        const u16* __restrict__ xsrc, const u16* __restrict__ Wt,
        const float* __restrict__ bias,
        const int* __restrict__ sample_list, const int4* __restrict__ tasks,
        const int* __restrict__ itemlist, void* __restrict__ outp) {
    int item = itemlist[blockIdx.x];
    if (item < 0) return;
    int4 task = tasks[item >> 2];
    int nb = item & 3;
    int ns = task.z;
    int e = task.x;
    int s0 = sample_list[task.y];
    int s1 = (ns > 1) ? sample_list[task.y + 1] : s0;  // dup reads, masked store
    int n0 = nb * 128;

    int tid = threadIdx.x;
    int lane = tid & 63, wv = tid >> 6;          // 4 waves
    int wr = wv >> 1, wc = wv & 1;               // 2x2 wave grid
    int quad = lane >> 4, c15 = lane & 15;
    int r8 = lane >> 3, cg = lane & 7;           // staging: row-in-group, chunk

    __shared__ __align__(16) u16 xs[2][128 * 64];   // 2 x 16 KB
    __shared__ __align__(16) u16 wt[2][128 * 64];   // 2 x 16 KB

    floatx4 acc[4][4];
    floatx4 zero4 = {0.f, 0.f, 0.f, 0.f};
#pragma unroll
    for (int i = 0; i < 4; i++)
#pragma unroll
        for (int j = 0; j < 4; j++) acc[i][j] = zero4;

    const u16* wbase = Wt + (size_t)(e * H_ + n0) * DIN;
    int kc_sw = (cg ^ r8) * 8;                   // swizzled global k-offset

    auto stage = [&](int b, int k0) {
#pragma unroll
        for (int h = 0; h < 4; h++) {
            int rbase = h * 32 + wv * 8;         // wave-uniform row-group base
            int s = (h < 2) ? s0 : s1;
            int t = (rbase + r8) & 63;
            gl2lds16(xsrc + ((size_t)s * T_ + t) * H_ + k0 + kc_sw,
                     &xs[b][rbase * 64]);
        }
#pragma unroll
        for (int h = 0; h < 4; h++) {
            int nbase = h * 32 + wv * 8;
            gl2lds16(wbase + (size_t)(nbase + r8) * DIN + k0 + kc_sw,
                     &wt[b][nbase * 64]);
        }
    };

    auto compute = [&](int b) {
#pragma unroll
        for (int kk = 0; kk < 2; kk++) {
            int c = kk * 4 + quad;               // k-chunk index 0..7
            short8 af[4], bfr[4];
#pragma unroll
            for (int i = 0; i < 4; i++) {
                int row = wr * 64 + i * 16 + c15;
                af[i] = *(const short8*)&xs[b][row * 64 + ((c ^ (row & 7)) * 8)];
                int nr = wc * 64 + i * 16 + c15;
                bfr[i] = *(const short8*)&wt[b][nr * 64 + ((c ^ (nr & 7)) * 8)];
            }
#pragma unroll
            for (int mt = 0; mt < 4; mt++)
#pragma unroll
                for (int nt = 0; nt < 4; nt++)
                    acc[mt][nt] = __builtin_amdgcn_mfma_f32_16x16x32_bf16(
                            af[mt], bfr[nt], acc[mt][nt], 0, 0, 0);
        }
    };

    constexpr int KI = DIN / 64;                 // 8 K-iterations
    stage(0, 0);
    __syncthreads();                             // drain prologue stage
#pragma unroll
    for (int t = 0; t < KI; ++t) {
        if (t + 1 < KI) stage((t + 1) & 1, (t + 1) * 64);  // issue-early
        compute(t & 1);                          // overlaps in-flight stage
        if (t + 1 < KI) __syncthreads();         // vmcnt(0) drain + barrier
    }

    // ---- epilogue: C/D layout col=c15, row=quad*4+r; wave-row wr = sample ----
    if (wr >= ns) return;
    int s = (wr == 0) ? s0 : s1;
    const float* bp = PSBIAS ? (bias + (size_t)s * H_)   // per-sample (GEMM2)
                             : (bias + (size_t)e * H_);  // per-expert (GEMM3)
#pragma unroll
    for (int mt = 0; mt < 4; mt++) {
        int tb = mt * 16 + quad * 4;             // t base within sample
#pragma unroll
        for (int nt = 0; nt < 4; nt++) {
            int col = n0 + wc * 64 + nt * 16 + c15;
            float bv = bp[col];
#pragma unroll
            for (int r = 0; r < 4; r++) {
                float v = acc[mt][nt][r] + bv;
                if (DO_SWISH) v = v / (1.0f + expf(-v));   // x*sigmoid(x)
                size_t oidx = ((size_t)s * T_ + tb + r) * H_ + col;
                if (OUT_BF16) ((u16*)outp)[oidx] = f2bf(v);
                else          ((float*)outp)[oidx] = v;
            }
        }
    }
}

// ---------------------------------------------------------------------------
extern "C" void kernel_launch(void* const* d_in, const int* in_sizes, int n_in,
                              void* d_out, int out_size, void* d_ws, size_t ws_size,
                              hipStream_t stream) {
    const float* actions   = (const float*)d_in[0];
    const float* timesteps = (const float*)d_in[1];
    const int*   cat_ids   = (const int*)d_in[2];
    const float* W1 = (const float*)d_in[3];
    const float* b1 = (const float*)d_in[4];
    const float* W2 = (const float*)d_in[5];
    const float* b2 = (const float*)d_in[6];
    const float* W3 = (const float*)d_in[7];
    const float* b3 = (const float*)d_in[8];

    // ws: a_emb 32MB (reused as Wt3 after GEMM2) | y 32MB | meta.
    // d_out (64 MiB) is scratch until GEMM3's epilogue:
    //   Wt2a bf16 16MiB @0 | bias2s f32 1MiB @48MiB | tauG f32 1MiB @52MiB.
    char* ws = (char*)d_ws;
    u16* a_emb = (u16*)ws;
    u16* y     = (u16*)(ws + (size_t)32 * 1024 * 1024);
    char* meta = ws + (size_t)64 * 1024 * 1024 + 512 * 1024;
    int*  sample_list = (int*)meta;                     // 2 KB
    int4* tasks       = (int4*)(meta + 8192);           // 272*16 B
    int*  itemlist    = (int*)(meta + 16384);           // GRID_*4 B
    int*  eoff        = (int*)(meta + 24576);           // 128 B
    int*  ecnt        = (int*)(meta + 24576 + 128);     // 128 B
    u16*  Wt2a   = (u16*)d_out;
    float* bias2s = (float*)((char*)d_out + (size_t)48 * 1024 * 1024);
    float* tauG   = (float*)((char*)d_out + (size_t)52 * 1024 * 1024);
    u16*  Wt3    = a_emb;

    hipLaunchKernelGGL(group_kernel, dim3(1), dim3(512), 0, stream,
                       cat_ids, sample_list, tasks, itemlist, eoff, ecnt);
    hipLaunchKernelGGL(embed_kernel, dim3(512), dim3(256), 0, stream,
                       actions, timesteps, cat_ids, W1, b1, b2, a_emb, tauG,
                       bias2s);
    hipLaunchKernelGGL(convert_transpose, dim3(H_ / 64, 2, E_), dim3(256),
                       0, stream, W2, Wt2a, 2 * H_, H_);
    hipLaunchKernelGGL(tau_bias_kernel, dim3(8, E_, 4), dim3(256), 0, stream,
                       W2, tauG, sample_list, eoff, ecnt, bias2s);
    hipLaunchKernelGGL((moe_gemm<H_, true, true, true>), dim3(GRID_),
                       dim3(256), 0, stream,
                       a_emb, Wt2a, bias2s, sample_list, tasks, itemlist,
                       (void*)y);
    hipLaunchKernelGGL(convert_transpose, dim3(H_ / 64, 2, E_), dim3(256),
                       0, stream, W3, Wt3, H_, H_);
    hipLaunchKernelGGL((moe_gemm<H_, false, false, false>), dim3(GRID_),
                       dim3(256), 0, stream,
                       y, Wt3, b3, sample_list, tasks, itemlist, d_out);
}

// Round 4
// 285.128 us; speedup vs baseline: 1.1512x; 1.0639x over previous
//
#include <hip/hip_runtime.h>
#include <hip/hip_bf16.h>

// Problem constants (from reference): B=512, T=64, A=32, H=512, E=32
#define B_ 512
#define T_ 64
#define A_ 32
#define H_ 512
#define E_ 32
#define MAX_TASKS 272   // sum_e ceil(cnt_e/2) <= 256 + 16
#define CAP_ 168        // itemlist capacity per XCD class
#define GRID_ (8 * CAP_)
#define TSC 16          // tau-bias samples per chunk

typedef unsigned short u16;
typedef unsigned int u32;
typedef __attribute__((ext_vector_type(8))) short short8;   // 8 bf16 (MFMA A/B frag)
typedef __attribute__((ext_vector_type(4))) float floatx4;  // MFMA C/D frag

static __device__ __forceinline__ u16 f2bf(float f) {
    u32 u = __builtin_bit_cast(u32, f);
    u += 0x7fffu + ((u >> 16) & 1u);   // RNE
    return (u16)(u >> 16);
}

// async global->LDS, 16B per lane; LDS dest is wave-uniform base (HW adds
// lane*16). Swizzle must be applied on the GLOBAL address per lane.
static __device__ __forceinline__ void gl2lds16(const u16* g, u16* l) {
    __builtin_amdgcn_global_load_lds(
        (const __attribute__((address_space(1))) void*)g,
        (__attribute__((address_space(3))) void*)l, 16, 0, 0);
}

// ---------------------------------------------------------------------------
// Launch 1 (FUSED): blocks [0,512) = per-sample embed work; block 512 = the
// grouping block (old group_kernel body, 512 threads). Fusing kills one
// launch gap; group and embed are independent (both read only inputs).
// Embed: GEMM1 (K=32, fp32 VALU, 1 col/thread) -> bf16 a_emb; tau table
// tauG[s][512] (2 trig/thread); bias2s[s][:] = b2[e(s)][:] (tau_bias adds).
// ---------------------------------------------------------------------------
__global__ __launch_bounds__(512) void embed_group_kernel(
        const float* __restrict__ actions, const float* __restrict__ timesteps,
        const int* __restrict__ cat_ids, const float* __restrict__ W1,
        const float* __restrict__ b1, const float* __restrict__ b2,
        u16* __restrict__ a_emb, float* __restrict__ tauG,
        float* __restrict__ bias2s,
        int* __restrict__ sample_list, int4* __restrict__ tasks,
        int* __restrict__ itemlist, int* __restrict__ eoff_g,
        int* __restrict__ ecnt_g) {
    int tid = threadIdx.x;

    if (blockIdx.x == B_) {
        // ------------------- grouping block (uniform branch) -------------------
        __shared__ int cnt[E_], off[E_], cur[E_], toff[E_], jc[8];
        __shared__ int total, fb;
        if (tid < E_) { cnt[tid] = 0; cur[tid] = 0; }
        __syncthreads();
        int e = cat_ids[tid];               // tid in [0,512) == B_
        atomicAdd(&cnt[e], 1);
        __syncthreads();
        if (tid == 0) {
            int run = 0, trun = 0;
            for (int i = 0; i < E_; i++) {
                off[i] = run;  run += cnt[i];
                toff[i] = trun; trun += (cnt[i] + 1) >> 1;
            }
            total = trun;
        }
        __syncthreads();
        if (tid < E_) {
            int c = cnt[tid], o = off[tid], to = toff[tid];
            eoff_g[tid] = o;
            ecnt_g[tid] = c;
            for (int j = 0; j < c; j += 2)
                tasks[to++] = make_int4(tid, o + j, (c - j >= 2) ? 2 : 1, 0);
        }
        if (tid < 8) {
            int J = 0;
            for (int cc = 0; cc < 4; cc++)
                J += 4 * ((cnt[tid + 8 * cc] + 1) >> 1);
            jc[tid] = J;
        }
        __syncthreads();
        if (tid == 0) {
            int f = 0;
            for (int x = 0; x < 8; x++) if (jc[x] > CAP_) f = 1;
            fb = f;
        }
        __syncthreads();
        if (!fb) {
            if (tid < 8) {
                int j = 0;
                for (int cc = 0; cc < 4; cc++) {
                    int ee = tid + 8 * cc;
                    int nt = (cnt[ee] + 1) >> 1, t0 = toff[ee];
                    for (int t = t0; t < t0 + nt; t++)
                        for (int nb = 0; nb < 4; nb++) {
                            itemlist[tid + 8 * j] = (t << 2) | nb;
                            j++;
                        }
                }
                for (; j < CAP_; j++) itemlist[tid + 8 * j] = -1;
            }
        } else {
            for (int f = tid; f < GRID_; f += 512)
                itemlist[f] = (f < 4 * total) ? f : -1;
        }
        int p = atomicAdd(&cur[e], 1);
        sample_list[off[e] + p] = tid;
        return;
    }

    // ---------------------------- embed block ----------------------------
    int b = blockIdx.x;
    int e = cat_ids[b];
    {
        float tval = timesteps[b];
        int kk = tid & 255;
        float freq = expf(-9.210340371976184f * (float)kk * (1.0f / 256.0f));
        float ang = tval * freq;
        tauG[(size_t)b * H_ + tid] = (tid < 256) ? sinf(ang) : cosf(ang);
        bias2s[(size_t)b * H_ + tid] = b2[e * H_ + tid];
    }

    __shared__ float act[T_ * A_];
    const float* asrc = actions + (size_t)b * T_ * A_;
    for (int i = tid; i < T_ * A_; i += 512) act[i] = asrc[i];
    __syncthreads();

    const float* w1 = W1 + (size_t)e * A_ * H_;
    float wcol[A_];
#pragma unroll
    for (int k = 0; k < A_; k++) wcol[k] = w1[k * H_ + tid];
    float bb = b1[e * H_ + tid];
    u16* orow = a_emb + (size_t)b * T_ * H_;
    for (int tt = 0; tt < T_; tt++) {
        float acc = bb;
#pragma unroll
        for (int k = 0; k < A_; k++)
            acc = fmaf(act[tt * A_ + k], wcol[k], acc);   // LDS broadcast
        orow[tt * H_ + tid] = f2bf(acc);
    }
}

// ---------------------------------------------------------------------------
// convert-transpose core: W [e][srcK][512] f32 rows [0,64) of k0 ->
// Wt [e][512][dstK] bf16. Each thread writes a full 128B contiguous run of
// its Wt row (whole L2 lines covered by one thread).
// ---------------------------------------------------------------------------
static __device__ __forceinline__ void ct_block(
        const float* __restrict__ W, u16* __restrict__ Wt,
        int srcK, int dstK, int e, int k0, int n) {
    const float* src = W + ((size_t)e * srcK + k0) * H_ + n;
    short8 out[8];
#pragma unroll
    for (int j = 0; j < 64; j++)
        out[j >> 3][j & 7] = (short)f2bf(src[(size_t)j * H_]);
    u16* dst = Wt + ((size_t)e * H_ + n) * dstK + k0;
#pragma unroll
    for (int c = 0; c < 8; c++) *(short8*)(dst + c * 8) = out[c];
}

// ---------------------------------------------------------------------------
// Kernel: standalone ct (used for W3 after GEMM2 frees the a_emb buffer).
// grid (dstK/64, 2, E_)
// ---------------------------------------------------------------------------
__global__ __launch_bounds__(256) void convert_transpose(
        const float* __restrict__ W, u16* __restrict__ Wt, int srcK, int dstK) {
    ct_block(W, Wt, srcK, dstK, blockIdx.z, blockIdx.x * 64,
             blockIdx.y * 256 + threadIdx.x);
}

// ---------------------------------------------------------------------------
// Launch 2 (FUSED): blocks [0,512) = ct of W2 rows [0,512) -> Wt2a;
// blocks [512,1536) = tau_bias: bias2s[s][n] += tauG_f32[s] . W2b_f32[e].
// tau_bias grid: 8cc x 32e x 4kq = 1024 blocks -> with ct = 6 blocks/CU.
// W2 read exactly once chip-wide across the two halves. k-quarter partials
// combined with hw f32 atomics into bias2s (pre-init'd to b2 in launch 1).
// ---------------------------------------------------------------------------
__global__ __launch_bounds__(256) void prep_kernel(
        const float* __restrict__ W2, u16* __restrict__ Wt2a,
        const float* __restrict__ tauG, const int* __restrict__ sample_list,
        const int* __restrict__ eoff, const int* __restrict__ ecnt,
        float* __restrict__ bias2s) {
    int tid = threadIdx.x;
    int bid = blockIdx.x;

    __shared__ float tauT[128][20];    // [k][sl], rows 80B (16B-aligned) 10KB
    __shared__ float pS[4][TSC][64];   // per-wave partials — 16 KB

    if (bid < 512) {
        int e = bid >> 4, sub = bid & 15;
        ct_block(W2, Wt2a, 2 * H_, H_, e, (sub & 7) * 64,
                 (sub >> 3) * 256 + tid);
        return;
    }

    int id = bid - 512;
    int cc = id & 7;              // 0..7: 64-col chunk
    int e  = (id >> 3) & 31;
    int kq = id >> 8;             // 0..3: 128-k quarter
    int cnt = ecnt[e], off = eoff[e];
    if (cnt == 0) return;
    int ks = tid >> 6;            // wave id = 32-k sub-block
    int ln = tid & 63;            // col within chunk
    int n = cc * 64 + ln;
    const float* wb = W2 + ((size_t)e * 1024 + 512 + kq * 128) * H_; // [k][n]

    for (int c0 = 0; c0 < cnt; c0 += TSC) {
        // stage tau slice transposed: [k][sl]; global reads 512B/row segments
        for (int i = tid; i < TSC * 128; i += 256) {
            int sl = i >> 7, k = i & 127;
            float v = 0.f;
            if (c0 + sl < cnt)
                v = tauG[(size_t)sample_list[off + c0 + sl] * H_ + kq * 128 + k];
            tauT[k][sl] = v;
        }
        __syncthreads();

        float a[TSC];
#pragma unroll
        for (int s = 0; s < TSC; s++) a[s] = 0.f;

#pragma unroll 8
        for (int j = 0; j < 32; j++) {
            int k = ks * 32 + j;
            float w = wb[(size_t)k * H_ + n];     // 256B/wave coalesced
            float tv[TSC];
            *(float4*)&tv[0]  = *(const float4*)&tauT[k][0];   // broadcast
            *(float4*)&tv[4]  = *(const float4*)&tauT[k][4];
            *(float4*)&tv[8]  = *(const float4*)&tauT[k][8];
            *(float4*)&tv[12] = *(const float4*)&tauT[k][12];
#pragma unroll
            for (int s = 0; s < TSC; s++) a[s] = fmaf(tv[s], w, a[s]);
        }

#pragma unroll
        for (int s = 0; s < TSC; s++) pS[ks][s][ln] = a[s];
        __syncthreads();

        for (int o = tid; o < TSC * 64; o += 256) {
            int sl = o >> 6, l = o & 63;
            if (c0 + sl < cnt) {
                float v = pS[0][sl][l] + pS[1][sl][l] +
                          pS[2][sl][l] + pS[3][sl][l];
                int s = sample_list[off + c0 + sl];
                unsafeAtomicAdd(&bias2s[(size_t)s * H_ + cc * 64 + l], v);
            }
        }
        __syncthreads();
    }
}

// ---------------------------------------------------------------------------
// Kernels GEMM2/GEMM3: expert-grouped MFMA GEMM, K=512 (tau folded out).
// Block: 256 threads (4 waves), tile M=128 (2 samples) x N=128, BK=64.
// Round-3 post-mortem: stage(t+1); compute(t); __syncthreads() was a fake
// pipeline — __syncthreads drains vmcnt(0) INCLUDING the just-issued t+1
// loads, exposing full staging latency at every barrier (MfmaUtil 14%).
// NEW: true 2-deep pipeline (T3+T4): raw s_barrier + counted vmcnt(8).
// Per iter: compute(t) -> s_barrier (all waves done reading buf[t&1]) ->
// stage(t+2) into buf[t&1] -> s_waitcnt vmcnt(8) (waits ONLY t+1's 8 loads;
// t+2's 8 stay in flight across the barrier) -> s_barrier -> next iter.
// Each wave waits only its own loads; barrier promotes that to all waves.
// Swizzle: 16B chunk c of row r at slot c^(r&7), applied on the global
// address side (gl2lds dest must be linear); frag reads conflict-free
// (SQ_LDS_BANK_CONFLICT = 0 measured).
// ---------------------------------------------------------------------------
template <int DIN, bool PSBIAS, bool DO_SWISH, bool OUT_BF16>
__global__ __launch_bounds__(256, 2) void moe_gemm(
        const u16* __restrict__ xsrc, const u16* __restrict__ Wt,
        const float* __restrict__ bias,
        const int* __restrict__ sample_list, const int4* __restrict__ tasks,
        const int* __restrict__ itemlist, void* __restrict__ outp) {
    int item = itemlist[blockIdx.x];
    if (item < 0) return;
    int4 task = tasks[item >> 2];
    int nb = item & 3;
    int ns = task.z;
    int e = task.x;
    int s0 = sample_list[task.y];
    int s1 = (ns > 1) ? sample_list[task.y + 1] : s0;  // dup reads, masked store
    int n0 = nb * 128;

    int tid = threadIdx.x;
    int lane = tid & 63, wv = tid >> 6;          // 4 waves
    int wr = wv >> 1, wc = wv & 1;               // 2x2 wave grid
    int quad = lane >> 4, c15 = lane & 15;
    int r8 = lane >> 3, cg = lane & 7;           // staging: row-in-group, chunk

    __shared__ __align__(16) u16 xs[2][128 * 64];   // 2 x 16 KB
    __shared__ __align__(16) u16 wt[2][128 * 64];   // 2 x 16 KB

    floatx4 acc[4][4];
    floatx4 zero4 = {0.f, 0.f, 0.f, 0.f};
#pragma unroll
    for (int i = 0; i < 4; i++)
#pragma unroll
        for (int j = 0; j < 4; j++) acc[i][j] = zero4;

    const u16* wbase = Wt + (size_t)(e * H_ + n0) * DIN;
    int kc_sw = (cg ^ r8) * 8;                   // swizzled global k-offset

    auto stage = [&](int b, int k0) {            // 8 loads per wave
#pragma unroll
        for (int h = 0; h < 4; h++) {
            int rbase = h * 32 + wv * 8;         // wave-uniform row-group base
            int s = (h < 2) ? s0 : s1;
            int t = (rbase + r8) & 63;
            gl2lds16(xsrc + ((size_t)s * T_ + t) * H_ + k0 + kc_sw,
                     &xs[b][rbase * 64]);
        }
#pragma unroll
        for (int h = 0; h < 4; h++) {
            int nbase = h * 32 + wv * 8;
            gl2lds16(wbase + (size_t)(nbase + r8) * DIN + k0 + kc_sw,
                     &wt[b][nbase * 64]);
        }
    };

    auto compute = [&](int b) {
#pragma unroll
        for (int kk = 0; kk < 2; kk++) {
            int c = kk * 4 + quad;               // k-chunk index 0..7
            short8 af[4], bfr[4];
#pragma unroll
            for (int i = 0; i < 4; i++) {
                int row = wr * 64 + i * 16 + c15;
                af[i] = *(const short8*)&xs[b][row * 64 + ((c ^ (row & 7)) * 8)];
                int nr = wc * 64 + i * 16 + c15;
                bfr[i] = *(const short8*)&wt[b][nr * 64 + ((c ^ (nr & 7)) * 8)];
            }
#pragma unroll
            for (int mt = 0; mt < 4; mt++)
#pragma unroll
                for (int nt = 0; nt < 4; nt++)
                    acc[mt][nt] = __builtin_amdgcn_mfma_f32_16x16x32_bf16(
                            af[mt], bfr[nt], acc[mt][nt], 0, 0, 0);
        }
    };

    constexpr int KI = DIN / 64;                 // 8 K-iterations
    stage(0, 0);                                 // 8 loads (buf0)
    stage(1, 64);                                // 8 loads (buf1)
    asm volatile("s_waitcnt vmcnt(8)" ::: "memory");  // own buf0 loads done
    __builtin_amdgcn_s_barrier();                // all waves' buf0 done
    __builtin_amdgcn_sched_barrier(0);
#pragma unroll
    for (int t = 0; t < KI; ++t) {
        compute(t & 1);
        if (t + 1 < KI) {
            __builtin_amdgcn_s_barrier();        // all waves done reading buf[t&1]
            __builtin_amdgcn_sched_barrier(0);
            if (t + 2 < KI) {
                stage(t & 1, (t + 2) * 64);      // buf[(t+2)&1] == buf[t&1]
                asm volatile("s_waitcnt vmcnt(8)" ::: "memory"); // t+1 done
            } else {
                asm volatile("s_waitcnt vmcnt(0)" ::: "memory"); // drain last
            }
            __builtin_amdgcn_s_barrier();        // all waves' t+1 loads done
            __builtin_amdgcn_sched_barrier(0);
        }
    }

    // ---- epilogue: C/D layout col=c15, row=quad*4+r; wave-row wr = sample ----
    if (wr >= ns) return;
    int s = (wr == 0) ? s0 : s1;
    const float* bp = PSBIAS ? (bias + (size_t)s * H_)   // per-sample (GEMM2)
                             : (bias + (size_t)e * H_);  // per-expert (GEMM3)
#pragma unroll
    for (int mt = 0; mt < 4; mt++) {
        int tb = mt * 16 + quad * 4;             // t base within sample
#pragma unroll
        for (int nt = 0; nt < 4; nt++) {
            int col = n0 + wc * 64 + nt * 16 + c15;
            float bv = bp[col];
#pragma unroll
            for (int r = 0; r < 4; r++) {
                float v = acc[mt][nt][r] + bv;
                if (DO_SWISH) v = v / (1.0f + expf(-v));   // x*sigmoid(x)
                size_t oidx = ((size_t)s * T_ + tb + r) * H_ + col;
                if (OUT_BF16) ((u16*)outp)[oidx] = f2bf(v);
                else          ((float*)outp)[oidx] = v;
            }
        }
    }
}

// ---------------------------------------------------------------------------
extern "C" void kernel_launch(void* const* d_in, const int* in_sizes, int n_in,
                              void* d_out, int out_size, void* d_ws, size_t ws_size,
                              hipStream_t stream) {
    const float* actions   = (const float*)d_in[0];
    const float* timesteps = (const float*)d_in[1];
    const int*   cat_ids   = (const int*)d_in[2];
    const float* W1 = (const float*)d_in[3];
    const float* b1 = (const float*)d_in[4];
    const float* W2 = (const float*)d_in[5];
    const float* b2 = (const float*)d_in[6];
    const float* W3 = (const float*)d_in[7];
    const float* b3 = (const float*)d_in[8];

    // ws: a_emb 32MB (reused as Wt3 after GEMM2) | y 32MB | meta.
    // d_out (64 MiB) is scratch until GEMM3's epilogue:
    //   Wt2a bf16 16MiB @0 | bias2s f32 1MiB @48MiB | tauG f32 1MiB @52MiB.
    char* ws = (char*)d_ws;
    u16* a_emb = (u16*)ws;
    u16* y     = (u16*)(ws + (size_t)32 * 1024 * 1024);
    char* meta = ws + (size_t)64 * 1024 * 1024 + 512 * 1024;
    int*  sample_list = (int*)meta;                     // 2 KB
    int4* tasks       = (int4*)(meta + 8192);           // 272*16 B
    int*  itemlist    = (int*)(meta + 16384);           // GRID_*4 B
    int*  eoff        = (int*)(meta + 24576);           // 128 B
    int*  ecnt        = (int*)(meta + 24576 + 128);     // 128 B
    u16*  Wt2a   = (u16*)d_out;
    float* bias2s = (float*)((char*)d_out + (size_t)48 * 1024 * 1024);
    float* tauG   = (float*)((char*)d_out + (size_t)52 * 1024 * 1024);
    u16*  Wt3    = a_emb;

    // Launch 1: embed (512 blocks) + group (block 512)
    hipLaunchKernelGGL(embed_group_kernel, dim3(B_ + 1), dim3(512), 0, stream,
                       actions, timesteps, cat_ids, W1, b1, b2,
                       a_emb, tauG, bias2s,
                       sample_list, tasks, itemlist, eoff, ecnt);
    // Launch 2: ct2 (512 blocks) + tau_bias (1024 blocks)
    hipLaunchKernelGGL(prep_kernel, dim3(1536), dim3(256), 0, stream,
                       W2, Wt2a, tauG, sample_list, eoff, ecnt, bias2s);
    // Launch 3: GEMM2
    hipLaunchKernelGGL((moe_gemm<H_, true, true, true>), dim3(GRID_),
                       dim3(256), 0, stream,
                       a_emb, Wt2a, bias2s, sample_list, tasks, itemlist,
                       (void*)y);
    // Launch 4: ct3 (a_emb buffer is dead now)
    hipLaunchKernelGGL(convert_transpose, dim3(H_ / 64, 2, E_), dim3(256),
                       0, stream, W3, Wt3, H_, H_);
    // Launch 5: GEMM3
    hipLaunchKernelGGL((moe_gemm<H_, false, false, false>), dim3(GRID_),
                       dim3(256), 0, stream,
                       y, Wt3, b3, sample_list, tasks, itemlist, d_out);
}